// Round 2
// baseline (182.171 us; speedup 1.0000x reference)
//
#include <hip/hip_runtime.h>
#include <cstdint>

constexpr int Bb = 8, Hh = 512, Ww = 512;
constexpr int HWn = Hh * Ww;          // 262144 = 2^18
constexpr int CH1  = 4;               // rows per block in k1  (was 8)
constexpr int CH23 = 8;               // rows per block in k23 (was 16)
constexpr int CHK4 = 4;               // rows per block in k4  (was 8)
constexpr int NBIN = 1024;            // percentile histogram bins over [0,1]

__device__ __forceinline__ int reflect_idx(int p, int n) {
    p = (p < 0) ? -p : p;
    return (p < n) ? p : (2 * n - 2 - p);
}
__device__ __forceinline__ int clamp_r(const int* rad) {
    int r = rad[0];
    return (r < 1) ? 1 : ((r > 50) ? 50 : r);
}

// ---------------- K1: multi-row -> horizontal box sums (float4) ----------------
// Each block: CH1 rows of one batch. t0 of previous row kept in LDS (no re-read).
__global__ __launch_bounds__(512) void k1_stats_h(
    const float* __restrict__ img, const float* __restrict__ omega,
    const float* __restrict__ atm, const int* __restrict__ rad,
    float4* __restrict__ hq, unsigned int* __restrict__ histzero)
{
    const int tile = blockIdx.x;
    const int b = blockIdx.y;
    const int y0 = tile * CH1;
    const int j = threadIdx.x;           // 512 threads = one per column
    const int fbid = b * gridDim.x + tile;
    if (fbid < 48) histzero[fbid * 512 + j] = 0u;   // zero 24*1024 hist bins
    const int r = clamp_r(rad);

    __shared__ float t0buf[2][512];
    __shared__ float4 Pb[512];
    __shared__ float4 wsum[8];

    const float om = omega[b];
    const float iA0 = 1.0f / (atm[b*3+0] + 1e-8f);
    const float iA1 = 1.0f / (atm[b*3+1] + 1e-8f);
    const float iA2 = 1.0f / (atm[b*3+2] + 1e-8f);
    const float* imb = img + (size_t)b * 3 * HWn;

    {   // preload t0 of row y0-1 (row 0 if y0==0; matches reference ip=max(i-1,0))
        const int yp = (y0 > 0) ? (y0 - 1) : 0;
        float r1 = imb[0*HWn + yp*Ww + j];
        float g1 = imb[1*HWn + yp*Ww + j];
        float b1 = imb[2*HWn + yp*Ww + j];
        t0buf[0][j] = 1.0f - om * fminf(fminf(r1*iA0, g1*iA1), b1*iA2);
    }
    __syncthreads();

    const int lane = j & 63, wv = j >> 6;
    int pv = 0;
    for (int k = 0; k < CH1; ++k) {
        const int y = y0 + k;
        float r0 = imb[0*HWn + y*Ww + j];
        float g0 = imb[1*HWn + y*Ww + j];
        float b0 = imb[2*HWn + y*Ww + j];
        float t0c = 1.0f - om * fminf(fminf(r0*iA0, g0*iA1), b0*iA2);
        float gr = 0.299f*r0 + 0.587f*g0 + 0.114f*b0;
        const float* t0p = t0buf[pv];
        t0buf[pv^1][j] = t0c;            // becomes prev row next iteration
        float tpj = t0p[j];              // prev-row reads fenced by prior barriers
        float tx  = (j == 0) ? t0p[0] : t0p[j-1] * __expf(-fabsf(tpj - t0p[j-1]));
        float tgv = (y == 0) ? tx : tx * __expf(-fabsf(t0c - tpj));

        float4 incl;
        incl.x = gr; incl.y = tgv; incl.z = gr * tgv; incl.w = gr * gr;
        #pragma unroll
        for (int off = 1; off < 64; off <<= 1) {
            float ux = __shfl_up(incl.x, off);
            float uy = __shfl_up(incl.y, off);
            float uz = __shfl_up(incl.z, off);
            float uw = __shfl_up(incl.w, off);
            if (lane >= off) { incl.x += ux; incl.y += uy; incl.z += uz; incl.w += uw; }
        }
        if (lane == 63) wsum[wv] = incl;
        __syncthreads();
        float4 o4; o4.x = 0.f; o4.y = 0.f; o4.z = 0.f; o4.w = 0.f;
        #pragma unroll
        for (int w = 0; w < 7; ++w) {
            if (w < wv) {
                float4 t = wsum[w];
                o4.x += t.x; o4.y += t.y; o4.z += t.z; o4.w += t.w;
            }
        }
        float4 P; P.x = incl.x + o4.x; P.y = incl.y + o4.y; P.z = incl.z + o4.z; P.w = incl.w + o4.w;
        Pb[j] = P;
        __syncthreads();

        const int lo = j - r, hi = j + r;
        float4 s = Pb[(hi > 511) ? 511 : hi];
        if (lo > 0) {
            float4 t = Pb[lo-1];
            s.x -= t.x; s.y -= t.y; s.z -= t.z; s.w -= t.w;
        }
        if (lo < 0) {
            float4 t = Pb[r - j], u = Pb[0];
            s.x += t.x - u.x; s.y += t.y - u.y; s.z += t.z - u.z; s.w += t.w - u.w;
        }
        if (hi > 511) {
            float4 t = Pb[510], u = Pb[1021 - j - r];
            s.x += t.x - u.x; s.y += t.y - u.y; s.z += t.z - u.z; s.w += t.w - u.w;
        }
        hq[((size_t)b * Hh + y) * Ww + j] = s;
        pv ^= 1;
    }
}

// ---- K23: vertical sliding box on hq -> a,b ; horizontal box of a,b -> hab ----
__global__ __launch_bounds__(512) void k23_ab_h(
    const float4* __restrict__ hq, const int* __restrict__ rad,
    float2* __restrict__ hab)
{
    const int b  = blockIdx.y;
    const int y0 = blockIdx.x * CH23;
    const int j  = threadIdx.x;
    const int r  = clamp_r(rad);
    const float ikk = 1.0f / (float)((2*r+1) * (2*r+1));
    const int lane = j & 63, wv = j >> 6;

    __shared__ float2 Pb8[CH23][512];    // 32 KB
    __shared__ float2 wsum8[CH23][8];

    const float4* hqb = hq + (size_t)b * Hh * Ww + j;
    float4 s; s.x = 0.f; s.y = 0.f; s.z = 0.f; s.w = 0.f;
    if (r == 15) {
        if (y0 >= 15 && y0 + 15 < Hh) {   // interior: pure immediate-offset burst
            #pragma unroll
            for (int d = -15; d <= 15; ++d) {
                float4 v = hqb[(size_t)(y0 + d) * Ww];
                s.x += v.x; s.y += v.y; s.z += v.z; s.w += v.w;
            }
        } else {
            #pragma unroll
            for (int d = -15; d <= 15; ++d) {
                int m = reflect_idx(y0 + d, Hh);
                float4 v = hqb[(size_t)m * Ww];
                s.x += v.x; s.y += v.y; s.z += v.z; s.w += v.w;
            }
        }
    } else {
        for (int d = -r; d <= r; ++d) {
            int m = reflect_idx(y0 + d, Hh);
            float4 v = hqb[(size_t)m * Ww];
            s.x += v.x; s.y += v.y; s.z += v.z; s.w += v.w;
        }
    }
    float av[CH23], bv[CH23];
    #pragma unroll
    for (int k = 0; k < CH23; ++k) {
        int y = y0 + k;
        float mI = s.x * ikk, mp = s.y * ikk, mIp = s.z * ikk, mII = s.w * ikk;
        float a = (mIp - mI * mp) / (mII - mI * mI + 0.5f);
        av[k] = a;
        bv[k] = mp - a * mI;
        int yin  = reflect_idx(y + 1 + r, Hh);
        int yout = reflect_idx(y - r, Hh);
        float4 vi = hqb[(size_t)yin  * Ww];
        float4 vo = hqb[(size_t)yout * Ww];
        s.x += vi.x - vo.x; s.y += vi.y - vo.y; s.z += vi.z - vo.z; s.w += vi.w - vo.w;
    }

    float ix[CH23], iy[CH23];
    #pragma unroll
    for (int k = 0; k < CH23; ++k) {
        float sx = av[k], sy = bv[k];
        #pragma unroll
        for (int off = 1; off < 64; off <<= 1) {
            float ux = __shfl_up(sx, off);
            float uy = __shfl_up(sy, off);
            if (lane >= off) { sx += ux; sy += uy; }
        }
        ix[k] = sx; iy[k] = sy;
        if (lane == 63) { wsum8[k][wv].x = sx; wsum8[k][wv].y = sy; }
    }
    __syncthreads();

    #pragma unroll
    for (int k = 0; k < CH23; ++k) {
        float ox = 0.f, oy = 0.f;
        #pragma unroll
        for (int w = 0; w < 7; ++w) {
            if (w < wv) { float2 t = wsum8[k][w]; ox += t.x; oy += t.y; }
        }
        Pb8[k][j].x = ix[k] + ox;
        Pb8[k][j].y = iy[k] + oy;
    }
    __syncthreads();

    const int lo = j - r, hi = j + r;
    const int him = (hi > 511) ? 511 : hi;
    #pragma unroll
    for (int k = 0; k < CH23; ++k) {
        float2 hs = Pb8[k][him];
        if (lo > 0)   { float2 t = Pb8[k][lo-1];  hs.x -= t.x; hs.y -= t.y; }
        if (lo < 0)   { float2 t = Pb8[k][r-j], u = Pb8[k][0];
                        hs.x += t.x - u.x; hs.y += t.y - u.y; }
        if (hi > 511) { float2 t = Pb8[k][510], u = Pb8[k][1021-j-r];
                        hs.x += t.x - u.x; hs.y += t.y - u.y; }
        hab[((size_t)b * Hh + (y0 + k)) * Ww + j] = hs;
    }
}

// ---- K4: vertical box of hab -> t -> J ; fused per-(b,c) histogram -------
__global__ __launch_bounds__(256) void k4_final_v(
    const float4* __restrict__ hab4, const float2* __restrict__ img2,
    const float* __restrict__ atm, const int* __restrict__ rad,
    float2* __restrict__ J2, unsigned int* __restrict__ hist)
{
    const int b   = blockIdx.y;
    const int y0  = blockIdx.x * CHK4;
    const int tid = threadIdx.x;             // float2-column 0..255
    const int r   = clamp_r(rad);
    const float ikk = 1.0f / (float)((2*r+1) * (2*r+1));
    const int HP4 = Ww / 2;                  // hab row pitch in float4 (256)
    const int CP2 = HWn / 2;                 // channel pitch in float2
    const int RP2 = Ww / 2;                  // img/J row pitch in float2 (256)

    __shared__ unsigned int lh[3 * NBIN];    // 12 KB
    for (int i = tid; i < 3 * NBIN; i += 256) lh[i] = 0u;
    __syncthreads();

    const float A0 = atm[b*3+0], A1 = atm[b*3+1], A2 = atm[b*3+2];
    const float2* imb = img2 + (size_t)b * 3 * CP2;
    float2*       Jb  = J2   + (size_t)b * 3 * CP2;
    const float4* habb = hab4 + (size_t)b * Hh * HP4 + tid;

    float2 V0, V1;
    V0.x = 0.f; V0.y = 0.f; V1.x = 0.f; V1.y = 0.f;
    if (r == 15) {
        if (y0 >= 15 && y0 + 15 < Hh) {      // interior: immediate-offset burst
            #pragma unroll
            for (int d = -15; d <= 15; ++d) {
                float4 h = habb[(size_t)(y0 + d) * HP4];
                V0.x += h.x; V0.y += h.y; V1.x += h.z; V1.y += h.w;
            }
        } else {
            #pragma unroll
            for (int d = -15; d <= 15; ++d) {
                int m = reflect_idx(y0 + d, Hh);
                float4 h = habb[(size_t)m * HP4];
                V0.x += h.x; V0.y += h.y; V1.x += h.z; V1.y += h.w;
            }
        }
    } else {
        for (int d = -r; d <= r; ++d) {
            int m = reflect_idx(y0 + d, Hh);
            float4 h = habb[(size_t)m * HP4];
            V0.x += h.x; V0.y += h.y; V1.x += h.z; V1.y += h.w;
        }
    }

    unsigned int clo0 = 0, chi0 = 0, clo1 = 0, chi1 = 0, clo2 = 0, chi2 = 0;

    #pragma unroll
    for (int k = 0; k < CHK4; ++k) {
        const int y = y0 + k;
        const int yin  = reflect_idx(y + 1 + r, Hh);
        const int yout = reflect_idx(y - r, Hh);
        float4 hi4 = habb[(size_t)yin  * HP4];
        float4 ho4 = habb[(size_t)yout * HP4];
        const size_t po = (size_t)y * RP2 + tid;
        float2 c0 = imb[0*CP2 + po];
        float2 c1 = imb[1*CP2 + po];
        float2 c2 = imb[2*CP2 + po];

        float jr[2], jg[2], jb[2];
        {   // q = 0 (pixel 2*tid)
            float g_ = 0.299f*c0.x + 0.587f*c1.x + 0.114f*c2.x;
            float t  = fminf(fmaxf((V0.x * g_ + V0.y) * ikk, 0.1f), 1.0f);
            float it = 1.0f / (t + 1e-8f);
            jr[0] = fminf(fmaxf((c0.x - A0) * it + A0, 0.f), 1.f);
            jg[0] = fminf(fmaxf((c1.x - A1) * it + A1, 0.f), 1.f);
            jb[0] = fminf(fmaxf((c2.x - A2) * it + A2, 0.f), 1.f);
        }
        {   // q = 1 (pixel 2*tid+1)
            float g_ = 0.299f*c0.y + 0.587f*c1.y + 0.114f*c2.y;
            float t  = fminf(fmaxf((V1.x * g_ + V1.y) * ikk, 0.1f), 1.0f);
            float it = 1.0f / (t + 1e-8f);
            jr[1] = fminf(fmaxf((c0.y - A0) * it + A0, 0.f), 1.f);
            jg[1] = fminf(fmaxf((c1.y - A1) * it + A1, 0.f), 1.f);
            jb[1] = fminf(fmaxf((c2.y - A2) * it + A2, 0.f), 1.f);
        }
        Jb[0*CP2 + po] = make_float2(jr[0], jr[1]);
        Jb[1*CP2 + po] = make_float2(jg[0], jg[1]);
        Jb[2*CP2 + po] = make_float2(jb[0], jb[1]);

        #pragma unroll
        for (int q = 0; q < 2; ++q) {
            int bR = (int)(jr[q] * (float)NBIN); bR = (bR > NBIN-1) ? NBIN-1 : bR;
            if (bR == 0) clo0++; else if (bR == NBIN-1) chi0++; else atomicAdd(&lh[0*NBIN + bR], 1u);
            int bG = (int)(jg[q] * (float)NBIN); bG = (bG > NBIN-1) ? NBIN-1 : bG;
            if (bG == 0) clo1++; else if (bG == NBIN-1) chi1++; else atomicAdd(&lh[1*NBIN + bG], 1u);
            int bB = (int)(jb[q] * (float)NBIN); bB = (bB > NBIN-1) ? NBIN-1 : bB;
            if (bB == 0) clo2++; else if (bB == NBIN-1) chi2++; else atomicAdd(&lh[2*NBIN + bB], 1u);
        }

        V0.x += hi4.x - ho4.x; V0.y += hi4.y - ho4.y;
        V1.x += hi4.z - ho4.z; V1.y += hi4.w - ho4.w;
    }

    if (clo0) atomicAdd(&lh[0*NBIN],            clo0);
    if (chi0) atomicAdd(&lh[0*NBIN + NBIN - 1], chi0);
    if (clo1) atomicAdd(&lh[1*NBIN],            clo1);
    if (chi1) atomicAdd(&lh[1*NBIN + NBIN - 1], chi1);
    if (clo2) atomicAdd(&lh[2*NBIN],            clo2);
    if (chi2) atomicAdd(&lh[2*NBIN + NBIN - 1], chi2);
    __syncthreads();

    const size_t hb = (size_t)b * 3 * NBIN;
    for (int i = tid; i < 3 * NBIN; i += 256) {
        unsigned int v = lh[i];
        if (v) atomicAdd(&hist[hb + i], v);
    }
}

// ---- K6: per-block percentile decide (wave 0) + in-place stretch ---------
__global__ __launch_bounds__(256) void k6_norm(
    float4* __restrict__ J4, const unsigned int* __restrict__ hist,
    const float* __restrict__ L_low, const float* __restrict__ L_high)
{
    const int bc  = blockIdx.x >> 6;         // 64 blocks per (b,c)
    const int sub = blockIdx.x & 63;
    const int b   = bc / 3;
    __shared__ float sp[2];

    if (threadIdx.x < 64) {
        const int lane = threadIdx.x;
        const unsigned int* hb = hist + (size_t)bc * NBIN;
        unsigned int loc[NBIN / 64];
        unsigned int lsum = 0;
        #pragma unroll
        for (int i = 0; i < NBIN / 64; ++i) { loc[i] = hb[lane * (NBIN/64) + i]; lsum += loc[i]; }
        unsigned int incl = lsum;
        #pragma unroll
        for (int off = 1; off < 64; off <<= 1) {
            unsigned int v = __shfl_up(incl, off);
            if (lane >= off) incl += v;
        }
        unsigned int excl = incl - lsum;
        #pragma unroll
        for (int t = 0; t < 2; ++t) {
            float L = t ? L_high[b] : L_low[b];
            int k = (int)(L * (1.0f / 100.0f) * (float)HWn);
            k = (k < 0) ? 0 : ((k > HWn - 1) ? HWn - 1 : k);
            if ((unsigned int)k >= excl && (unsigned int)k < incl) {
                unsigned int c = excl;
                #pragma unroll
                for (int i = 0; i < NBIN / 64; ++i) {
                    if ((unsigned int)k < c + loc[i]) {
                        sp[t] = ((float)(lane * (NBIN/64) + i) + 0.5f) * (1.0f / (float)NBIN);
                        break;
                    }
                    c += loc[i];
                }
            }
        }
    }
    __syncthreads();

    const float l = sp[0], h = sp[1];
    const float inv = 1.0f / (h - l + 1e-8f);
    float4* base = J4 + (size_t)bc * (HWn / 4) + (size_t)sub * 1024;
    #pragma unroll
    for (int s = 0; s < 4; ++s) {
        const int idx = threadIdx.x + s * 256;
        float4 v = base[idx];
        v.x = fminf(fmaxf((fminf(fmaxf(v.x, l), h) - l) * inv, 0.f), 1.f);
        v.y = fminf(fmaxf((fminf(fmaxf(v.y, l), h) - l) * inv, 0.f), 1.f);
        v.z = fminf(fmaxf((fminf(fmaxf(v.z, l), h) - l) * inv, 0.f), 1.f);
        v.w = fminf(fmaxf((fminf(fmaxf(v.w, l), h) - l) * inv, 0.f), 1.f);
        base[idx] = v;
    }
}

extern "C" void kernel_launch(void* const* d_in, const int* in_sizes, int n_in,
                              void* d_out, int out_size, void* d_ws, size_t ws_size,
                              hipStream_t stream)
{
    const float* img    = (const float*)d_in[0];
    const float* omega  = (const float*)d_in[1];
    const float* atm    = (const float*)d_in[2];
    const float* L_low  = (const float*)d_in[3];
    const float* L_high = (const float*)d_in[4];
    const int*   rad    = (const int*)d_in[5];
    float* J  = (float*)d_out;
    float* ws = (float*)d_ws;

    const size_t F = (size_t)Bb * HWn;           // 2097152 px per field
    float4* hq  = (float4*)ws;                   // [0,4F) floats (32 MB)
    float2* hab = (float2*)(ws + 4 * F);         // [4F,6F)      (16 MB)
    unsigned int* hist = (unsigned int*)(ws + 6 * F);   // [24][1024]
    // k1 zeroes hist (48*512 = 24576 = 24*1024 uints) as a side duty.

    k1_stats_h<<<dim3(Hh/CH1,  Bb), 512, 0, stream>>>(img, omega, atm, rad, hq, hist);
    k23_ab_h  <<<dim3(Hh/CH23, Bb), 512, 0, stream>>>(hq, rad, hab);
    k4_final_v<<<dim3(Hh/CHK4, Bb), 256, 0, stream>>>((const float4*)hab, (const float2*)img, atm, rad, (float2*)J, hist);
    k6_norm   <<<24 * 64, 256, 0, stream>>>((float4*)J, hist, L_low, L_high);
}

// Round 3
// 169.441 us; speedup vs baseline: 1.0751x; 1.0751x over previous
//
#include <hip/hip_runtime.h>
#include <cstdint>

constexpr int Bb = 8, Hh = 512, Ww = 512;
constexpr int HWn = Hh * Ww;          // 262144 = 2^18
constexpr int CH1  = 8;               // rows per block in k1 (== vertical chunk size)
constexpr int CH23 = 8;               // rows per block in k23 (== chunk size, aligned)
constexpr int CHK4 = 4;               // rows per block in k4
constexpr int NBIN = 1024;            // percentile histogram bins over [0,1]
constexpr int NCHK = Hh / 8;          // 64 vertical chunks of 8 rows

__device__ __forceinline__ int reflect_idx(int p, int n) {
    p = (p < 0) ? -p : p;
    return (p < n) ? p : (2 * n - 2 - p);
}
__device__ __forceinline__ int clamp_r(const int* rad) {
    int r = rad[0];
    return (r < 1) ? 1 : ((r > 50) ? 50 : r);
}
__device__ __forceinline__ float4 f4add(float4 a, float4 b) {
    return make_float4(a.x + b.x, a.y + b.y, a.z + b.z, a.w + b.w);
}
__device__ __forceinline__ float4 f4sub(float4 a, float4 b) {
    return make_float4(a.x - b.x, a.y - b.y, a.z - b.z, a.w - b.w);
}

// Sum of rows a..b (0<=a<=b<512) of a chunked-prefix field.
// P = per-column pointer to intra-8-row-chunk inclusive prefixes (row stride = pitch)
// T = per-column pointer to chunk totals (chunk stride = pitch)
__device__ __forceinline__ float4 ps_range(const float4* __restrict__ P,
                                           const float4* __restrict__ T,
                                           int a, int b, int pitch) {
    float4 res = P[(size_t)b * pitch];
    int cs;
    if (a > 0) {
        res = f4sub(res, P[(size_t)(a - 1) * pitch]);
        cs = (a - 1) >> 3;
    } else {
        cs = 0;
    }
    const int cb = b >> 3;
    for (int c = cs; c < cb; ++c)
        res = f4add(res, T[(size_t)c * pitch]);
    return res;
}

// Reflect-padded vertical window sum of radius r centered at row y.
__device__ __forceinline__ float4 win_sum(const float4* __restrict__ P,
                                          const float4* __restrict__ T,
                                          int y, int r, int pitch) {
    const int lo = y - r, hi = y + r;
    const int a = lo < 0 ? 0 : lo;
    const int b = hi > Hh - 1 ? Hh - 1 : hi;
    float4 s = ps_range(P, T, a, b, pitch);
    if (lo < 0)      s = f4add(s, ps_range(P, T, 1, -lo, pitch));
    if (hi > Hh - 1) s = f4add(s, ps_range(P, T, 2 * Hh - 2 - hi, Hh - 2, pitch));
    return s;
}

// ---------------- K1: rows -> horizontal box sums, written as 8-row vertical
//                  chunk prefixes P1 + chunk totals T1 ----------------
__global__ __launch_bounds__(512) void k1_stats_h(
    const float* __restrict__ img, const float* __restrict__ omega,
    const float* __restrict__ atm, const int* __restrict__ rad,
    float4* __restrict__ P1, float4* __restrict__ T1,
    unsigned int* __restrict__ histzero)
{
    const int tile = blockIdx.x;         // == chunk index (CH1 == 8)
    const int b = blockIdx.y;
    const int y0 = tile * CH1;
    const int j = threadIdx.x;           // 512 threads = one per column
    const int fbid = b * gridDim.x + tile;
    if (fbid < 48) histzero[fbid * 512 + j] = 0u;   // zero 24*1024 hist bins
    const int r = clamp_r(rad);

    __shared__ float t0buf[2][512];
    __shared__ float4 Pb[512];
    __shared__ float4 wsum[8];

    const float om = omega[b];
    const float iA0 = 1.0f / (atm[b*3+0] + 1e-8f);
    const float iA1 = 1.0f / (atm[b*3+1] + 1e-8f);
    const float iA2 = 1.0f / (atm[b*3+2] + 1e-8f);
    const float* imb = img + (size_t)b * 3 * HWn;

    {   // preload t0 of row y0-1 (row 0 if y0==0; matches reference ip=max(i-1,0))
        const int yp = (y0 > 0) ? (y0 - 1) : 0;
        float r1 = imb[0*HWn + yp*Ww + j];
        float g1 = imb[1*HWn + yp*Ww + j];
        float b1 = imb[2*HWn + yp*Ww + j];
        t0buf[0][j] = 1.0f - om * fminf(fminf(r1*iA0, g1*iA1), b1*iA2);
    }
    __syncthreads();

    const int lane = j & 63, wv = j >> 6;
    int pv = 0;
    float4 pacc = make_float4(0.f, 0.f, 0.f, 0.f);
    for (int k = 0; k < CH1; ++k) {
        const int y = y0 + k;
        float r0 = imb[0*HWn + y*Ww + j];
        float g0 = imb[1*HWn + y*Ww + j];
        float b0 = imb[2*HWn + y*Ww + j];
        float t0c = 1.0f - om * fminf(fminf(r0*iA0, g0*iA1), b0*iA2);
        float gr = 0.299f*r0 + 0.587f*g0 + 0.114f*b0;
        const float* t0p = t0buf[pv];
        t0buf[pv^1][j] = t0c;            // becomes prev row next iteration
        float tpj = t0p[j];              // prev-row reads fenced by prior barriers
        float tx  = (j == 0) ? t0p[0] : t0p[j-1] * __expf(-fabsf(tpj - t0p[j-1]));
        float tgv = (y == 0) ? tx : tx * __expf(-fabsf(t0c - tpj));

        float4 incl;
        incl.x = gr; incl.y = tgv; incl.z = gr * tgv; incl.w = gr * gr;
        #pragma unroll
        for (int off = 1; off < 64; off <<= 1) {
            float ux = __shfl_up(incl.x, off);
            float uy = __shfl_up(incl.y, off);
            float uz = __shfl_up(incl.z, off);
            float uw = __shfl_up(incl.w, off);
            if (lane >= off) { incl.x += ux; incl.y += uy; incl.z += uz; incl.w += uw; }
        }
        if (lane == 63) wsum[wv] = incl;
        __syncthreads();
        float4 o4 = make_float4(0.f, 0.f, 0.f, 0.f);
        #pragma unroll
        for (int w = 0; w < 7; ++w) {
            if (w < wv) o4 = f4add(o4, wsum[w]);
        }
        float4 P = f4add(incl, o4);
        Pb[j] = P;
        __syncthreads();

        const int lo = j - r, hi = j + r;
        float4 s = Pb[(hi > 511) ? 511 : hi];
        if (lo > 0)   s = f4sub(s, Pb[lo-1]);
        if (lo < 0)   s = f4add(s, f4sub(Pb[r - j], Pb[0]));
        if (hi > 511) s = f4add(s, f4sub(Pb[510], Pb[1021 - j - r]));

        pacc = f4add(pacc, s);           // intra-chunk vertical prefix
        P1[((size_t)b * Hh + y) * Ww + j] = pacc;
        pv ^= 1;
    }
    T1[((size_t)b * NCHK + tile) * Ww + j] = pacc;   // chunk total
}

// ---- K23: vertical box from P1/T1 -> a,b ; horizontal box -> P2/T2 -------
__global__ __launch_bounds__(512) void k23_ab_h(
    const float4* __restrict__ P1, const float4* __restrict__ T1,
    const int* __restrict__ rad,
    float2* __restrict__ P2, float2* __restrict__ T2)
{
    const int b  = blockIdx.y;
    const int y0 = blockIdx.x * CH23;    // chunk-aligned
    const int j  = threadIdx.x;
    const int r  = clamp_r(rad);
    const float ikk = 1.0f / (float)((2*r+1) * (2*r+1));
    const int lane = j & 63, wv = j >> 6;

    __shared__ float2 Pb8[CH23][512];    // 32 KB
    __shared__ float2 wsum8[CH23][8];

    const float4* Pj = P1 + (size_t)b * Hh * Ww + j;    // row stride Ww
    const float4* Tj = T1 + (size_t)b * NCHK * Ww + j;  // chunk stride Ww

    float av[CH23], bv[CH23];
    if (r == 15 && y0 >= 16 && y0 <= Hh - 24) {
        // interior fast path: chunk window is c0-2..c0+1
        const int c0 = y0 >> 3;
        float4 Ta = Tj[(size_t)(c0-2) * Ww];
        float4 Tb = Tj[(size_t)(c0-1) * Ww];
        float4 Tc = Tj[(size_t)(c0  ) * Ww];
        float4 Td = Tj[(size_t)(c0+1) * Ww];
        float4 TTb0 = f4add(f4add(Ta, Tb), Tc);
        float4 TTb1 = f4add(TTb0, Td);
        #pragma unroll
        for (int k = 0; k < CH23; ++k) {
            float4 Phi = Pj[(size_t)(y0 + k + 15) * Ww];
            float4 Plo = Pj[(size_t)(y0 + k - 16) * Ww];
            float4 W = f4sub(f4add(Phi, (k == 0) ? TTb0 : TTb1), Plo);
            float mI = W.x * ikk, mp = W.y * ikk, mIp = W.z * ikk, mII = W.w * ikk;
            float a = (mIp - mI * mp) / (mII - mI * mI + 0.5f);
            av[k] = a;
            bv[k] = mp - a * mI;
        }
    } else {
        for (int k = 0; k < CH23; ++k) {
            float4 W = win_sum(Pj, Tj, y0 + k, r, Ww);
            float mI = W.x * ikk, mp = W.y * ikk, mIp = W.z * ikk, mII = W.w * ikk;
            float a = (mIp - mI * mp) / (mII - mI * mI + 0.5f);
            av[k] = a;
            bv[k] = mp - a * mI;
        }
    }

    float ix[CH23], iy[CH23];
    #pragma unroll
    for (int k = 0; k < CH23; ++k) {
        float sx = av[k], sy = bv[k];
        #pragma unroll
        for (int off = 1; off < 64; off <<= 1) {
            float ux = __shfl_up(sx, off);
            float uy = __shfl_up(sy, off);
            if (lane >= off) { sx += ux; sy += uy; }
        }
        ix[k] = sx; iy[k] = sy;
        if (lane == 63) { wsum8[k][wv].x = sx; wsum8[k][wv].y = sy; }
    }
    __syncthreads();

    #pragma unroll
    for (int k = 0; k < CH23; ++k) {
        float ox = 0.f, oy = 0.f;
        #pragma unroll
        for (int w = 0; w < 7; ++w) {
            if (w < wv) { float2 t = wsum8[k][w]; ox += t.x; oy += t.y; }
        }
        Pb8[k][j].x = ix[k] + ox;
        Pb8[k][j].y = iy[k] + oy;
    }
    __syncthreads();

    const int lo = j - r, hi = j + r;
    const int him = (hi > 511) ? 511 : hi;
    float2 hacc; hacc.x = 0.f; hacc.y = 0.f;
    #pragma unroll
    for (int k = 0; k < CH23; ++k) {
        float2 hs = Pb8[k][him];
        if (lo > 0)   { float2 t = Pb8[k][lo-1];  hs.x -= t.x; hs.y -= t.y; }
        if (lo < 0)   { float2 t = Pb8[k][r-j], u = Pb8[k][0];
                        hs.x += t.x - u.x; hs.y += t.y - u.y; }
        if (hi > 511) { float2 t = Pb8[k][510], u = Pb8[k][1021-j-r];
                        hs.x += t.x - u.x; hs.y += t.y - u.y; }
        hacc.x += hs.x; hacc.y += hs.y;            // intra-chunk vertical prefix
        P2[((size_t)b * Hh + (y0 + k)) * Ww + j] = hacc;
    }
    T2[((size_t)b * NCHK + (y0 >> 3)) * Ww + j] = hacc;   // chunk total
}

// ---- K4: vertical box of hab from P2/T2 -> t -> J ; fused histogram ------
__global__ __launch_bounds__(256) void k4_final_v(
    const float4* __restrict__ P2f4, const float4* __restrict__ T2f4,
    const float2* __restrict__ img2,
    const float* __restrict__ atm, const int* __restrict__ rad,
    float2* __restrict__ J2, unsigned int* __restrict__ hist)
{
    const int b   = blockIdx.y;
    const int y0  = blockIdx.x * CHK4;
    const int tid = threadIdx.x;             // float4-column (2 pixels) 0..255
    const int r   = clamp_r(rad);
    const float ikk = 1.0f / (float)((2*r+1) * (2*r+1));
    const int HP4 = Ww / 2;                  // P2/T2 row pitch in float4 (256)
    const int CP2 = HWn / 2;                 // channel pitch in float2
    const int RP2 = Ww / 2;                  // img/J row pitch in float2 (256)

    __shared__ unsigned int lh[3 * NBIN];    // 12 KB
    for (int i = tid; i < 3 * NBIN; i += 256) lh[i] = 0u;
    __syncthreads();

    const float A0 = atm[b*3+0], A1 = atm[b*3+1], A2 = atm[b*3+2];
    const float2* imb = img2 + (size_t)b * 3 * CP2;
    float2*       Jb  = J2   + (size_t)b * 3 * CP2;
    const float4* Pj  = P2f4 + (size_t)b * Hh * HP4 + tid;   // row stride HP4
    const float4* Tj  = T2f4 + (size_t)b * NCHK * HP4 + tid; // chunk stride HP4

    // vertical window sums for the CHK4 rows: W[k] = {a0,b0,a1,b1}
    float4 Wk[CHK4];
    if (r == 15 && y0 >= 16 && y0 <= Hh - 20) {
        const int c0 = y0 >> 3;              // floor; base chunk = c0-2 for all k
        const int off = y0 & 7;              // 0 or 4
        float4 Ta = Tj[(size_t)(c0-2) * HP4];
        float4 Tb = Tj[(size_t)(c0-1) * HP4];
        float4 Tc = Tj[(size_t)(c0  ) * HP4];
        float4 Td = Tj[(size_t)(c0+1) * HP4];
        float4 TTb0 = f4add(f4add(Ta, Tb), Tc);
        float4 TTb1 = f4add(TTb0, Td);
        #pragma unroll
        for (int k = 0; k < CHK4; ++k) {
            float4 Phi = Pj[(size_t)(y0 + k + 15) * HP4];
            float4 Plo = Pj[(size_t)(y0 + k - 16) * HP4];
            Wk[k] = f4sub(f4add(Phi, (k == 0 && off == 0) ? TTb0 : TTb1), Plo);
        }
    } else {
        #pragma unroll
        for (int k = 0; k < CHK4; ++k)
            Wk[k] = win_sum(Pj, Tj, y0 + k, r, HP4);
    }

    unsigned int clo0 = 0, chi0 = 0, clo1 = 0, chi1 = 0, clo2 = 0, chi2 = 0;

    #pragma unroll
    for (int k = 0; k < CHK4; ++k) {
        const int y = y0 + k;
        const size_t po = (size_t)y * RP2 + tid;
        float2 c0v = imb[0*CP2 + po];
        float2 c1v = imb[1*CP2 + po];
        float2 c2v = imb[2*CP2 + po];

        float jr[2], jg[2], jb[2];
        {   // pixel 2*tid
            float g_ = 0.299f*c0v.x + 0.587f*c1v.x + 0.114f*c2v.x;
            float t  = fminf(fmaxf((Wk[k].x * g_ + Wk[k].y) * ikk, 0.1f), 1.0f);
            float it = 1.0f / (t + 1e-8f);
            jr[0] = fminf(fmaxf((c0v.x - A0) * it + A0, 0.f), 1.f);
            jg[0] = fminf(fmaxf((c1v.x - A1) * it + A1, 0.f), 1.f);
            jb[0] = fminf(fmaxf((c2v.x - A2) * it + A2, 0.f), 1.f);
        }
        {   // pixel 2*tid+1
            float g_ = 0.299f*c0v.y + 0.587f*c1v.y + 0.114f*c2v.y;
            float t  = fminf(fmaxf((Wk[k].z * g_ + Wk[k].w) * ikk, 0.1f), 1.0f);
            float it = 1.0f / (t + 1e-8f);
            jr[1] = fminf(fmaxf((c0v.y - A0) * it + A0, 0.f), 1.f);
            jg[1] = fminf(fmaxf((c1v.y - A1) * it + A1, 0.f), 1.f);
            jb[1] = fminf(fmaxf((c2v.y - A2) * it + A2, 0.f), 1.f);
        }
        Jb[0*CP2 + po] = make_float2(jr[0], jr[1]);
        Jb[1*CP2 + po] = make_float2(jg[0], jg[1]);
        Jb[2*CP2 + po] = make_float2(jb[0], jb[1]);

        #pragma unroll
        for (int q = 0; q < 2; ++q) {
            int bR = (int)(jr[q] * (float)NBIN); bR = (bR > NBIN-1) ? NBIN-1 : bR;
            if (bR == 0) clo0++; else if (bR == NBIN-1) chi0++; else atomicAdd(&lh[0*NBIN + bR], 1u);
            int bG = (int)(jg[q] * (float)NBIN); bG = (bG > NBIN-1) ? NBIN-1 : bG;
            if (bG == 0) clo1++; else if (bG == NBIN-1) chi1++; else atomicAdd(&lh[1*NBIN + bG], 1u);
            int bB = (int)(jb[q] * (float)NBIN); bB = (bB > NBIN-1) ? NBIN-1 : bB;
            if (bB == 0) clo2++; else if (bB == NBIN-1) chi2++; else atomicAdd(&lh[2*NBIN + bB], 1u);
        }
    }

    if (clo0) atomicAdd(&lh[0*NBIN],            clo0);
    if (chi0) atomicAdd(&lh[0*NBIN + NBIN - 1], chi0);
    if (clo1) atomicAdd(&lh[1*NBIN],            clo1);
    if (chi1) atomicAdd(&lh[1*NBIN + NBIN - 1], chi1);
    if (clo2) atomicAdd(&lh[2*NBIN],            clo2);
    if (chi2) atomicAdd(&lh[2*NBIN + NBIN - 1], chi2);
    __syncthreads();

    const size_t hb = (size_t)b * 3 * NBIN;
    for (int i = tid; i < 3 * NBIN; i += 256) {
        unsigned int v = lh[i];
        if (v) atomicAdd(&hist[hb + i], v);
    }
}

// ---- K6: per-block percentile decide (wave 0) + in-place stretch ---------
__global__ __launch_bounds__(256) void k6_norm(
    float4* __restrict__ J4, const unsigned int* __restrict__ hist,
    const float* __restrict__ L_low, const float* __restrict__ L_high)
{
    const int bc  = blockIdx.x >> 6;         // 64 blocks per (b,c)
    const int sub = blockIdx.x & 63;
    const int b   = bc / 3;
    __shared__ float sp[2];

    if (threadIdx.x < 64) {
        const int lane = threadIdx.x;
        const unsigned int* hb = hist + (size_t)bc * NBIN;
        unsigned int loc[NBIN / 64];
        unsigned int lsum = 0;
        #pragma unroll
        for (int i = 0; i < NBIN / 64; ++i) { loc[i] = hb[lane * (NBIN/64) + i]; lsum += loc[i]; }
        unsigned int incl = lsum;
        #pragma unroll
        for (int off = 1; off < 64; off <<= 1) {
            unsigned int v = __shfl_up(incl, off);
            if (lane >= off) incl += v;
        }
        unsigned int excl = incl - lsum;
        #pragma unroll
        for (int t = 0; t < 2; ++t) {
            float L = t ? L_high[b] : L_low[b];
            int k = (int)(L * (1.0f / 100.0f) * (float)HWn);
            k = (k < 0) ? 0 : ((k > HWn - 1) ? HWn - 1 : k);
            if ((unsigned int)k >= excl && (unsigned int)k < incl) {
                unsigned int c = excl;
                #pragma unroll
                for (int i = 0; i < NBIN / 64; ++i) {
                    if ((unsigned int)k < c + loc[i]) {
                        sp[t] = ((float)(lane * (NBIN/64) + i) + 0.5f) * (1.0f / (float)NBIN);
                        break;
                    }
                    c += loc[i];
                }
            }
        }
    }
    __syncthreads();

    const float l = sp[0], h = sp[1];
    const float inv = 1.0f / (h - l + 1e-8f);
    float4* base = J4 + (size_t)bc * (HWn / 4) + (size_t)sub * 1024;
    #pragma unroll
    for (int s = 0; s < 4; ++s) {
        const int idx = threadIdx.x + s * 256;
        float4 v = base[idx];
        v.x = fminf(fmaxf((fminf(fmaxf(v.x, l), h) - l) * inv, 0.f), 1.f);
        v.y = fminf(fmaxf((fminf(fmaxf(v.y, l), h) - l) * inv, 0.f), 1.f);
        v.z = fminf(fmaxf((fminf(fmaxf(v.z, l), h) - l) * inv, 0.f), 1.f);
        v.w = fminf(fmaxf((fminf(fmaxf(v.w, l), h) - l) * inv, 0.f), 1.f);
        base[idx] = v;
    }
}

extern "C" void kernel_launch(void* const* d_in, const int* in_sizes, int n_in,
                              void* d_out, int out_size, void* d_ws, size_t ws_size,
                              hipStream_t stream)
{
    const float* img    = (const float*)d_in[0];
    const float* omega  = (const float*)d_in[1];
    const float* atm    = (const float*)d_in[2];
    const float* L_low  = (const float*)d_in[3];
    const float* L_high = (const float*)d_in[4];
    const int*   rad    = (const int*)d_in[5];
    float* J  = (float*)d_out;
    float* ws = (float*)d_ws;

    const size_t F = (size_t)Bb * HWn;           // 2097152 px per field
    float4* P1 = (float4*)ws;                    // [0,4F) floats   (32 MB)
    float2* P2 = (float2*)(ws + 4 * F);          // [4F,6F)         (16 MB)
    float4* T1 = (float4*)(ws + 6 * F);          // [6F,6.5F)       (4 MB)
    float2* T2 = (float2*)(ws + 6 * F + F / 2);  // [6.5F,6.75F)    (2 MB)
    unsigned int* hist = (unsigned int*)(ws + 6 * F + F / 2 + F / 4);
    // k1 zeroes hist (48*512 = 24576 = 24*1024 uints) as a side duty.

    k1_stats_h<<<dim3(Hh/CH1,  Bb), 512, 0, stream>>>(img, omega, atm, rad, P1, T1, hist);
    k23_ab_h  <<<dim3(Hh/CH23, Bb), 512, 0, stream>>>(P1, T1, rad, P2, T2);
    k4_final_v<<<dim3(Hh/CHK4, Bb), 256, 0, stream>>>((const float4*)P2, (const float4*)T2,
                                                      (const float2*)img, atm, rad,
                                                      (float2*)J, hist);
    k6_norm   <<<24 * 64, 256, 0, stream>>>((float4*)J, hist, L_low, L_high);
}